// Round 1
// baseline (139.367 us; speedup 1.0000x reference)
//
#include <hip/hip_runtime.h>
#include <cmath>

#define NWP 128
#define BLOCK 256

__global__ __launch_bounds__(BLOCK) void magnet_scan_kernel(
    const float* __restrict__ points,
    const float* __restrict__ centers,
    const float* __restrict__ raw_moment,
    const float* __restrict__ raw_dwell,
    float* __restrict__ out,
    int n_points,
    float eff_r2)
{
    __shared__ float s_cx[NWP], s_cy[NWP], s_cz[NWP];
    __shared__ float s_mx[NWP], s_my[NWP], s_mz[NWP];
    __shared__ float s_dt[NWP], s_hr2[NWP], s_cxy2[NWP];

    // Stage per-waypoint derived values into LDS (threads 0..127)
    int lt = threadIdx.x;
    if (lt < NWP) {
        float cx = centers[3 * lt + 0];
        float cy = centers[3 * lt + 1];
        float cz = centers[3 * lt + 2];
        s_cx[lt] = cx;
        s_cy[lt] = cy;
        s_cz[lt] = cz;
        s_mx[lt] = 0.05f * tanhf(raw_moment[3 * lt + 0]);
        s_my[lt] = 0.05f * tanhf(raw_moment[3 * lt + 1]);
        s_mz[lt] = 0.05f * tanhf(raw_moment[3 * lt + 2]);
        float sig = 1.0f / (1.0f + expf(-raw_dwell[lt]));
        s_dt[lt] = 0.01f + 0.19f * sig;
        s_hr2[lt] = fmaxf(eff_r2 - cz * cz, 0.0f);
        s_cxy2[lt] = cx * cx + cy * cy;
    }
    __syncthreads();

    int i = blockIdx.x * BLOCK + threadIdx.x;
    if (i >= n_points) return;

    float px = points[3 * i + 0];
    float py = points[3 * i + 1];
    float pz = points[3 * i + 2];  // 0 in practice, but keep general
    float pxy2 = px * px + py * py;

    float ox = 0.0f, oy = 0.0f, oz = 1.0f;
    float at = 0.0f, peak = 0.0f;

    const float RELAX_KEEP = 0.90483741803595957f;  // exp(-0.1)
    const float PI_F = 3.14159265358979323846f;

    #pragma unroll 4
    for (int k = 0; k < NWP; ++k) {
        float cx = s_cx[k], cy = s_cy[k], cz = s_cz[k];
        float mx = s_mx[k], my = s_my[k], mz = s_mz[k];
        float dt = s_dt[k], hr2 = s_hr2[k], cxy2 = s_cxy2[k];

        float rx = px - cx, ry = py - cy, rz = pz - cz;
        float r2 = fmaxf(rx * rx + ry * ry + rz * rz, 1e-12f);
        float r = sqrtf(r2);
        float inv_r3 = 1.0f / (r2 * r);
        float inv_r5 = inv_r3 / r2;
        float mdotr = rx * mx + ry * my + rz * mz;
        float s3 = 3.0f * (mdotr * inv_r5);
        float fx = rx * s3 - mx * inv_r3;
        float fy = ry * s3 - my * inv_r3;
        float fz = rz * s3 - mz * inv_r3;
        float bmag = sqrtf(fx * fx + fy * fy + fz * fz);
        float inv_b = 1.0f / fmaxf(bmag, 1e-12f);
        float bx = fx * inv_b, by = fy * inv_b, bz = fz * inv_b;

        float dxy2 = pxy2 + cxy2 - 2.0f * (px * cx + py * cy);
        bool cand = dxy2 <= hr2;

        // cross = orient x bdir
        float crx = oy * bz - oz * by;
        float cry = oz * bx - ox * bz;
        float crz = ox * by - oy * bx;
        float axis_norm = sqrtf(crx * crx + cry * cry + crz * crz);
        float sin_t = fminf(fmaxf(axis_norm, 0.0f), 1.0f);
        float cos_t = fminf(fmaxf(ox * bx + oy * by + oz * bz, -1.0f), 1.0f);

        float torque = (1e-14f * bmag) * sin_t;
        bool active = torque > 1e-19f;
        float rate = (1e-14f * bmag) / 1e-16f;

        float tan_half = sin_t / fmaxf(1.0f + cos_t, 1e-12f);
        float theta = atan2f(sin_t, cos_t);
        float theta_new = 2.0f * atanf(tan_half * expf(-rate * dt));
        float rot = active ? fminf(fmaxf(theta - theta_new, 0.0f), PI_F) : 0.0f;

        float inv_an = 1.0f / fmaxf(axis_norm, 1e-12f);
        float ux = crx * inv_an, uy = cry * inv_an, uz = crz * inv_an;
        float ca = cosf(rot);
        float sa = sinf(rot);
        // unit x orient
        float vx = uy * oz - uz * oy;
        float vy = uz * ox - ux * oz;
        float vz = ux * oy - uy * ox;
        float udoto = ux * ox + uy * oy + uz * oz;
        float omca = 1.0f - ca;
        float rox = ox * ca + vx * sa + ux * (udoto * omca);
        float roy = oy * ca + vy * sa + uy * (udoto * omca);
        float roz = oz * ca + vz * sa + uz * (udoto * omca);

        bool use_rot = (axis_norm > 1e-6f) && cand;
        ox = use_rot ? rox : ox;
        oy = use_rot ? roy : oy;
        oz = use_rot ? roz : oz;

        at += (cand && active) ? dt : 0.0f;

        float bxy = sqrtf(fx * fx + fy * fy);
        float contrib = cand ? bxy : 0.0f;
        peak = fmaxf(peak * RELAX_KEEP, contrib);
    }

    out[5 * i + 0] = ox;
    out[5 * i + 1] = oy;
    out[5 * i + 2] = oz;
    out[5 * i + 3] = at;
    out[5 * i + 4] = peak;
}

extern "C" void kernel_launch(void* const* d_in, const int* in_sizes, int n_in,
                              void* d_out, int out_size, void* d_ws, size_t ws_size,
                              hipStream_t stream) {
    const float* points = (const float*)d_in[0];
    const float* centers = (const float*)d_in[1];
    const float* raw_moment = (const float*)d_in[2];
    const float* raw_dwell = (const float*)d_in[3];
    float* out = (float*)d_out;

    int n_points = in_sizes[0] / 3;

    // eff_r2 = (2 * sqrt(3)*0.05 / (1e-19/1e-14))^(2/3), computed in double like Python
    double friction_thr = 1e-19 / 1e-14;
    double moment_norm = std::sqrt(3.0) * 0.05;
    float eff_r2 = (float)std::pow(2.0 * moment_norm / friction_thr, 2.0 / 3.0);

    int grid = (n_points + BLOCK - 1) / BLOCK;
    magnet_scan_kernel<<<grid, BLOCK, 0, stream>>>(points, centers, raw_moment,
                                                   raw_dwell, out, n_points, eff_r2);
}

// Round 5
// 138.037 us; speedup vs baseline: 1.0096x; 1.0096x over previous
//
#include <hip/hip_runtime.h>
#include <cmath>

#define NWP 128
#define BLOCK 256

// r5: decisive infra probe — byte-for-byte the round-1 math (proven pass,
// absmax 512, 91 us), only the kernel symbol renamed. No d_ws usage.
__global__ __launch_bounds__(BLOCK) void magnet_field_scan_r5(
    const float* __restrict__ points,
    const float* __restrict__ centers,
    const float* __restrict__ raw_moment,
    const float* __restrict__ raw_dwell,
    float* __restrict__ out,
    int n_points,
    float eff_r2)
{
    __shared__ float s_cx[NWP], s_cy[NWP], s_cz[NWP];
    __shared__ float s_mx[NWP], s_my[NWP], s_mz[NWP];
    __shared__ float s_dt[NWP], s_hr2[NWP], s_cxy2[NWP];

    int lt = threadIdx.x;
    if (lt < NWP) {
        float cx = centers[3 * lt + 0];
        float cy = centers[3 * lt + 1];
        float cz = centers[3 * lt + 2];
        s_cx[lt] = cx;
        s_cy[lt] = cy;
        s_cz[lt] = cz;
        s_mx[lt] = 0.05f * tanhf(raw_moment[3 * lt + 0]);
        s_my[lt] = 0.05f * tanhf(raw_moment[3 * lt + 1]);
        s_mz[lt] = 0.05f * tanhf(raw_moment[3 * lt + 2]);
        float sig = 1.0f / (1.0f + expf(-raw_dwell[lt]));
        s_dt[lt] = 0.01f + 0.19f * sig;
        s_hr2[lt] = fmaxf(eff_r2 - cz * cz, 0.0f);
        s_cxy2[lt] = cx * cx + cy * cy;
    }
    __syncthreads();

    int i = blockIdx.x * BLOCK + threadIdx.x;
    if (i >= n_points) return;

    float px = points[3 * i + 0];
    float py = points[3 * i + 1];
    float pz = points[3 * i + 2];
    float pxy2 = px * px + py * py;

    float ox = 0.0f, oy = 0.0f, oz = 1.0f;
    float at = 0.0f, peak = 0.0f;

    const float RELAX_KEEP = 0.90483741803595957f;  // exp(-0.1)
    const float PI_F = 3.14159265358979323846f;

    #pragma unroll 4
    for (int k = 0; k < NWP; ++k) {
        float cx = s_cx[k], cy = s_cy[k], cz = s_cz[k];
        float mx = s_mx[k], my = s_my[k], mz = s_mz[k];
        float dt = s_dt[k], hr2 = s_hr2[k], cxy2 = s_cxy2[k];

        float rx = px - cx, ry = py - cy, rz = pz - cz;
        float r2 = fmaxf(rx * rx + ry * ry + rz * rz, 1e-12f);
        float r = sqrtf(r2);
        float inv_r3 = 1.0f / (r2 * r);
        float inv_r5 = inv_r3 / r2;
        float mdotr = rx * mx + ry * my + rz * mz;
        float s3 = 3.0f * (mdotr * inv_r5);
        float fx = rx * s3 - mx * inv_r3;
        float fy = ry * s3 - my * inv_r3;
        float fz = rz * s3 - mz * inv_r3;
        float bmag = sqrtf(fx * fx + fy * fy + fz * fz);
        float inv_b = 1.0f / fmaxf(bmag, 1e-12f);
        float bx = fx * inv_b, by = fy * inv_b, bz = fz * inv_b;

        float dxy2 = pxy2 + cxy2 - 2.0f * (px * cx + py * cy);
        bool cand = dxy2 <= hr2;

        // cross = orient x bdir
        float crx = oy * bz - oz * by;
        float cry = oz * bx - ox * bz;
        float crz = ox * by - oy * bx;
        float axis_norm = sqrtf(crx * crx + cry * cry + crz * crz);
        float sin_t = fminf(fmaxf(axis_norm, 0.0f), 1.0f);
        float cos_t = fminf(fmaxf(ox * bx + oy * by + oz * bz, -1.0f), 1.0f);

        float torque = (1e-14f * bmag) * sin_t;
        bool active = torque > 1e-19f;
        float rate = (1e-14f * bmag) / 1e-16f;

        float tan_half = sin_t / fmaxf(1.0f + cos_t, 1e-12f);
        float theta = atan2f(sin_t, cos_t);
        float theta_new = 2.0f * atanf(tan_half * expf(-rate * dt));
        float rot = active ? fminf(fmaxf(theta - theta_new, 0.0f), PI_F) : 0.0f;

        float inv_an = 1.0f / fmaxf(axis_norm, 1e-12f);
        float ux = crx * inv_an, uy = cry * inv_an, uz = crz * inv_an;
        float ca = cosf(rot);
        float sa = sinf(rot);
        // unit x orient
        float vx = uy * oz - uz * oy;
        float vy = uz * ox - ux * oz;
        float vz = ux * oy - uy * ox;
        float udoto = ux * ox + uy * oy + uz * oz;
        float omca = 1.0f - ca;
        float rox = ox * ca + vx * sa + ux * (udoto * omca);
        float roy = oy * ca + vy * sa + uy * (udoto * omca);
        float roz = oz * ca + vz * sa + uz * (udoto * omca);

        bool use_rot = (axis_norm > 1e-6f) && cand;
        ox = use_rot ? rox : ox;
        oy = use_rot ? roy : oy;
        oz = use_rot ? roz : oz;

        at += (cand && active) ? dt : 0.0f;

        float bxy = sqrtf(fx * fx + fy * fy);
        float contrib = cand ? bxy : 0.0f;
        peak = fmaxf(peak * RELAX_KEEP, contrib);
    }

    out[5 * i + 0] = ox;
    out[5 * i + 1] = oy;
    out[5 * i + 2] = oz;
    out[5 * i + 3] = at;
    out[5 * i + 4] = peak;
}

extern "C" void kernel_launch(void* const* d_in, const int* in_sizes, int n_in,
                              void* d_out, int out_size, void* d_ws, size_t ws_size,
                              hipStream_t stream) {
    const float* points = (const float*)d_in[0];
    const float* centers = (const float*)d_in[1];
    const float* raw_moment = (const float*)d_in[2];
    const float* raw_dwell = (const float*)d_in[3];
    float* out = (float*)d_out;
    (void)d_ws; (void)ws_size;

    int n_points = in_sizes[0] / 3;

    // eff_r2 computed in double exactly like the Python host code
    double friction_thr = 1e-19 / 1e-14;
    double moment_norm = std::sqrt(3.0) * 0.05;
    float eff_r2 = (float)std::pow(2.0 * moment_norm / friction_thr, 2.0 / 3.0);

    int grid = (n_points + BLOCK - 1) / BLOCK;
    magnet_field_scan_r5<<<grid, BLOCK, 0, stream>>>(points, centers, raw_moment,
                                                     raw_dwell, out, n_points, eff_r2);
}

// Round 6
// 95.985 us; speedup vs baseline: 1.4520x; 1.4381x over previous
//
#include <hip/hip_runtime.h>
#include <cmath>

#define NWP 128
#define BLOCK 256

// r6: identity-math (no trig/div/sqrt libm in loop) + the round-2-4 bug fix:
// (ca,sa) must be renormalized to the unit circle. Without it, ca^2+sa^2 =
// cos_t^2+sin_t^2 = |o|^2-ish, and Rodrigues amplifies |o| exponentially
// (eps doubles/step -> the deterministic 7.7e15 blowup of rounds 2-4).
// Normalized (ca,sa) == (cos,sin)(atan2(sin_t,cos_t) - theta_new) exactly,
// i.e. the reference semantics. o is also renormalized each step (drift
// guard; O(1e-5) deviation, threshold 2.28e4).
__global__ __launch_bounds__(BLOCK) void magnet_scan_r6(
    const float* __restrict__ points,
    const float* __restrict__ centers,
    const float* __restrict__ raw_moment,
    const float* __restrict__ raw_dwell,
    float* __restrict__ out,
    int n_points,
    float eff_r2)
{
    // s_c[k] = {cx, cy, cz, hp}   hp = max(eff_r2 - cz^2, 0) - (cx^2 + cy^2)
    // s_m[k] = {mx, my, mz, dt}
    __shared__ float4 s_c[NWP];
    __shared__ float4 s_m[NWP];

    {
        const int lt = threadIdx.x;
        if (lt < NWP) {
            const float cx = centers[3 * lt + 0];
            const float cy = centers[3 * lt + 1];
            const float cz = centers[3 * lt + 2];
            const float mx = 0.05f * tanhf(raw_moment[3 * lt + 0]);
            const float my = 0.05f * tanhf(raw_moment[3 * lt + 1]);
            const float mz = 0.05f * tanhf(raw_moment[3 * lt + 2]);
            const float sig = 1.0f / (1.0f + expf(-raw_dwell[lt]));
            const float dtv = 0.01f + 0.19f * sig;
            const float hr2 = fmaxf(eff_r2 - cz * cz, 0.0f);
            const float hp = hr2 - (cx * cx + cy * cy);
            s_c[lt] = make_float4(cx, cy, cz, hp);
            s_m[lt] = make_float4(mx, my, mz, dtv);
        }
    }
    __syncthreads();

    const int i = blockIdx.x * BLOCK + threadIdx.x;
    if (i >= n_points) return;

    const float px = points[3 * i + 0];
    const float py = points[3 * i + 1];
    const float pz = points[3 * i + 2];
    const float pxy2 = px * px + py * py;

    float ox = 0.0f, oy = 0.0f, oz = 1.0f;
    float at = 0.0f, peak = 0.0f;

    const float RELAX_KEEP = 0.90483741803595957f;  // exp(-0.1)

    #pragma unroll 4
    for (int k = 0; k < NWP; ++k) {
        const float4 c4 = s_c[k];  // wave-uniform -> ds_read_b128 broadcast
        const float4 m4 = s_m[k];

        // dipole field
        const float rx = px - c4.x, ry = py - c4.y, rz = pz - c4.z;
        const float r2 = fmaxf(rx * rx + ry * ry + rz * rz, 1e-12f);
        const float inv_r  = __builtin_amdgcn_rsqf(r2);
        const float inv_r2 = inv_r * inv_r;
        const float inv_r3 = inv_r2 * inv_r;
        const float inv_r5 = inv_r3 * inv_r2;
        const float mdotr = rx * m4.x + ry * m4.y + rz * m4.z;
        const float s3 = 3.0f * mdotr * inv_r5;
        const float fx = rx * s3 - m4.x * inv_r3;
        const float fy = ry * s3 - m4.y * inv_r3;
        const float fz = rz * s3 - m4.z * inv_r3;
        const float b2 = fmaxf(fx * fx + fy * fy + fz * fz, 1e-24f);
        const float inv_b = __builtin_amdgcn_rsqf(b2);
        const float bmag = b2 * inv_b;
        const float bx = fx * inv_b, by = fy * inv_b, bz = fz * inv_b;

        // candidate test: pxy2 - 2*(px*cx+py*cy) <= hr2 - cxy2 (= c4.w)
        const bool cand = (pxy2 - 2.0f * (px * c4.x + py * c4.y)) <= c4.w;

        // cross = orient x bdir
        const float crx = oy * bz - oz * by;
        const float cry = oz * bx - ox * bz;
        const float crz = ox * by - oy * bx;
        const float an2 = crx * crx + cry * cry + crz * crz;
        const float inv_an = __builtin_amdgcn_rsqf(fmaxf(an2, 1e-24f));
        const float axis_norm = an2 * inv_an;
        const float sin_t = fminf(axis_norm, 1.0f);
        const float cos_t = fminf(fmaxf(ox * bx + oy * by + oz * bz, -1.0f), 1.0f);

        const bool active = (1e-14f * bmag) * sin_t > 1e-19f;

        // rotation via half-angle / angle-difference identities (no trig)
        const float e = __expf(-100.0f * bmag * m4.w);  // rate = 100*bmag
        const float th = sin_t * __builtin_amdgcn_rcpf(fmaxf(1.0f + cos_t, 1e-12f));
        const float w = th * e;
        const float w2 = w * w;
        const float dn = __builtin_amdgcn_rcpf(1.0f + w2);
        const float cn = (1.0f - w2) * dn;
        const float sn = (2.0f * w) * dn;
        float ca = cos_t * cn + sin_t * sn;
        float sa = sin_t * cn - cos_t * sn;
        // THE FIX: project (ca,sa) onto the unit circle == reference's
        // cos/sin(atan2(sin_t,cos_t) - theta_new). Prevents exponential
        // |o| amplification.
        {
            const float s2c = fmaxf(ca * ca + sa * sa, 1e-24f);
            const float inv_s = __builtin_amdgcn_rsqf(s2c);
            ca *= inv_s;
            sa *= inv_s;
        }
        ca = active ? ca : 1.0f;
        sa = active ? sa : 0.0f;

        // Rodrigues rotation about unit axis u = cross/|cross|
        const float ux = crx * inv_an, uy = cry * inv_an, uz = crz * inv_an;
        const float vx = uy * oz - uz * oy;
        const float vy = uz * ox - ux * oz;
        const float vz = ux * oy - uy * ox;
        const float udoto = ux * ox + uy * oy + uz * oz;
        const float omca = 1.0f - ca;
        const float rox = ox * ca + vx * sa + ux * (udoto * omca);
        const float roy = oy * ca + vy * sa + uy * (udoto * omca);
        const float roz = oz * ca + vz * sa + uz * (udoto * omca);

        const bool use_rot = (axis_norm > 1e-6f) && cand;
        ox = use_rot ? rox : ox;
        oy = use_rot ? roy : oy;
        oz = use_rot ? roz : oz;

        // drift guard: keep o unit (reference keeps it unit implicitly)
        {
            const float on2 = fmaxf(ox * ox + oy * oy + oz * oz, 1e-24f);
            const float inv_on = __builtin_amdgcn_rsqf(on2);
            ox *= inv_on;
            oy *= inv_on;
            oz *= inv_on;
        }

        at += (cand && active) ? m4.w : 0.0f;

        const float bxy = __builtin_amdgcn_sqrtf(fx * fx + fy * fy);
        peak = fmaxf(peak * RELAX_KEEP, cand ? bxy : 0.0f);
    }

    out[5 * i + 0] = ox;
    out[5 * i + 1] = oy;
    out[5 * i + 2] = oz;
    out[5 * i + 3] = at;
    out[5 * i + 4] = peak;
}

extern "C" void kernel_launch(void* const* d_in, const int* in_sizes, int n_in,
                              void* d_out, int out_size, void* d_ws, size_t ws_size,
                              hipStream_t stream) {
    const float* points = (const float*)d_in[0];
    const float* centers = (const float*)d_in[1];
    const float* raw_moment = (const float*)d_in[2];
    const float* raw_dwell = (const float*)d_in[3];
    float* out = (float*)d_out;
    (void)d_ws; (void)ws_size;

    const int n_points = in_sizes[0] / 3;

    // eff_r2 computed in double exactly like the Python host code
    const double friction_thr = 1e-19 / 1e-14;
    const double moment_norm = std::sqrt(3.0) * 0.05;
    const float eff_r2 = (float)std::pow(2.0 * moment_norm / friction_thr, 2.0 / 3.0);

    const int grid = (n_points + BLOCK - 1) / BLOCK;
    magnet_scan_r6<<<grid, BLOCK, 0, stream>>>(points, centers, raw_moment,
                                               raw_dwell, out, n_points, eff_r2);
}

// Round 7
// 88.286 us; speedup vs baseline: 1.5786x; 1.0872x over previous
//
#include <hip/hip_runtime.h>
#include <cmath>

#define NWP 128
#define BLOCK 256

// r7: in-plane rotation replaces Rodrigues.
//   new_o = bhat*cos(tn) + (o - bhat*cos(t)) * sin(tn)/sin(t)
// with cos(tn), sin(tn) from the exact-unit half-angle forms:
//   w = tan(t/2)*exp(-rate*dt);  cn=(1-w^2)/(1+w^2);  sn=2w/(1+w^2)
// (cn^2+sn^2 == 1 structurally -> no norm amplification, no repair rsq).
// sin(t) = sqrt(1-cos^2 t) stands in for |o x bhat| (o kept unit by renorm).
// Effective update condition == reference: active && sin>1e-6 && cand.
// exp in log2 domain: e = exp2(bmag * q), q = -100*dt/ln2 precomputed.
// at = (-ln2/100) * sum(q | cand&active).
__global__ __launch_bounds__(BLOCK, 1) void magnet_scan_r7(
    const float* __restrict__ points,
    const float* __restrict__ centers,
    const float* __restrict__ raw_moment,
    const float* __restrict__ raw_dwell,
    float* __restrict__ out,
    int n_points,
    float eff_r2)
{
    // s_c[k] = {cx, cy, cz, hp}   hp = max(eff_r2 - cz^2, 0) - (cx^2 + cy^2)
    // s_m[k] = {mx, my, mz, q}    q  = -(100/ln2) * dt
    __shared__ float4 s_c[NWP];
    __shared__ float4 s_m[NWP];

    {
        const int lt = threadIdx.x;
        if (lt < NWP) {
            const float cx = centers[3 * lt + 0];
            const float cy = centers[3 * lt + 1];
            const float cz = centers[3 * lt + 2];
            const float mx = 0.05f * tanhf(raw_moment[3 * lt + 0]);
            const float my = 0.05f * tanhf(raw_moment[3 * lt + 1]);
            const float mz = 0.05f * tanhf(raw_moment[3 * lt + 2]);
            const float sig = 1.0f / (1.0f + expf(-raw_dwell[lt]));
            const float dtv = 0.01f + 0.19f * sig;
            const float hr2 = fmaxf(eff_r2 - cz * cz, 0.0f);
            const float hp = hr2 - (cx * cx + cy * cy);
            s_c[lt] = make_float4(cx, cy, cz, hp);
            s_m[lt] = make_float4(mx, my, mz, -144.26950408889634f * dtv);
        }
    }
    __syncthreads();

    const int i = blockIdx.x * BLOCK + threadIdx.x;
    if (i >= n_points) return;

    const float px = points[3 * i + 0];
    const float py = points[3 * i + 1];
    const float pz = points[3 * i + 2];
    const float pxy2 = px * px + py * py;

    float ox = 0.0f, oy = 0.0f, oz = 1.0f;
    float qsum = 0.0f, peak = 0.0f;

    const float RELAX_KEEP = 0.90483741803595957f;  // exp(-0.1)

    #pragma unroll 8
    for (int k = 0; k < NWP; ++k) {
        const float4 c4 = s_c[k];  // wave-uniform -> ds_read_b128 broadcast
        const float4 m4 = s_m[k];

        // ---- o-independent field math (pipelines across iterations) ----
        const float rx = px - c4.x, ry = py - c4.y, rz = pz - c4.z;
        const float r2 = fmaxf(rx * rx + ry * ry + rz * rz, 1e-12f);
        const float inv_r  = __builtin_amdgcn_rsqf(r2);
        const float inv_r2 = inv_r * inv_r;
        const float inv_r3 = inv_r2 * inv_r;
        const float inv_r5 = inv_r3 * inv_r2;
        const float mdotr = rx * m4.x + ry * m4.y + rz * m4.z;
        const float s3 = 3.0f * mdotr * inv_r5;
        const float fx = rx * s3 - m4.x * inv_r3;
        const float fy = ry * s3 - m4.y * inv_r3;
        const float fz = rz * s3 - m4.z * inv_r3;
        const float b2 = fmaxf(fx * fx + fy * fy + fz * fz, 1e-24f);
        const float inv_b = __builtin_amdgcn_rsqf(b2);
        const float bmag = b2 * inv_b;
        const float e = __builtin_amdgcn_exp2f(bmag * m4.w);  // exp(-rate*dt)
        const bool cand = (pxy2 - 2.0f * (px * c4.x + py * c4.y)) <= c4.w;
        const float bxy = __builtin_amdgcn_sqrtf(fx * fx + fy * fy);

        // ---- o-dependent chain ----
        const float od = ox * fx + oy * fy + oz * fz;
        const float cos_t = fminf(fmaxf(od * inv_b, -1.0f), 1.0f);
        const float s2 = fmaxf((1.0f - cos_t) * (1.0f + cos_t), 0.0f);
        const float sin_t = __builtin_amdgcn_sqrtf(s2);

        const bool active = bmag * sin_t > 1e-5f;  // torque > friction

        const float th = sin_t * __builtin_amdgcn_rcpf(fmaxf(1.0f + cos_t, 1e-12f));
        const float w = th * e;
        const float w2 = w * w;
        const float dn = __builtin_amdgcn_rcpf(1.0f + w2);
        const float cn = (1.0f - w2) * dn;          // cos(theta_new), unit circle
        const float sn = (2.0f * w) * dn;           // sin(theta_new)
        const float ratio = sn * __builtin_amdgcn_rcpf(fmaxf(sin_t, 1e-12f));

        // new_o = f*(inv_b*cn) + (o - f*(inv_b*cos_t)) * ratio
        const float g = inv_b * cn;
        const float h = inv_b * cos_t;
        const float qx = ox - fx * h;
        const float qy = oy - fy * h;
        const float qz = oz - fz * h;
        float nx = fx * g + qx * ratio;
        float ny = fy * g + qy * ratio;
        float nz = fz * g + qz * ratio;

        const bool use_rot = active && cand && (sin_t > 1e-6f);
        nx = use_rot ? nx : ox;
        ny = use_rot ? ny : oy;
        nz = use_rot ? nz : oz;

        // renorm (drift guard)
        const float on2 = fmaxf(nx * nx + ny * ny + nz * nz, 1e-24f);
        const float inv_on = __builtin_amdgcn_rsqf(on2);
        ox = nx * inv_on;
        oy = ny * inv_on;
        oz = nz * inv_on;

        qsum += (cand && active) ? m4.w : 0.0f;
        peak = fmaxf(peak * RELAX_KEEP, cand ? bxy : 0.0f);
    }

    out[5 * i + 0] = ox;
    out[5 * i + 1] = oy;
    out[5 * i + 2] = oz;
    out[5 * i + 3] = qsum * -0.0069314718055994531f;  // -(ln2/100)
    out[5 * i + 4] = peak;
}

extern "C" void kernel_launch(void* const* d_in, const int* in_sizes, int n_in,
                              void* d_out, int out_size, void* d_ws, size_t ws_size,
                              hipStream_t stream) {
    const float* points = (const float*)d_in[0];
    const float* centers = (const float*)d_in[1];
    const float* raw_moment = (const float*)d_in[2];
    const float* raw_dwell = (const float*)d_in[3];
    float* out = (float*)d_out;
    (void)d_ws; (void)ws_size;

    const int n_points = in_sizes[0] / 3;

    // eff_r2 computed in double exactly like the Python host code
    const double friction_thr = 1e-19 / 1e-14;
    const double moment_norm = std::sqrt(3.0) * 0.05;
    const float eff_r2 = (float)std::pow(2.0 * moment_norm / friction_thr, 2.0 / 3.0);

    const int grid = (n_points + BLOCK - 1) / BLOCK;
    magnet_scan_r7<<<grid, BLOCK, 0, stream>>>(points, centers, raw_moment,
                                               raw_dwell, out, n_points, eff_r2);
}